// Round 7
// baseline (253.552 us; speedup 1.0000x reference)
//
#include <hip/hip_runtime.h>

// CANet fused kernel, round 7.
// r6 structure (composed conv+GEMM1, direct MFMA-from-inS) with the d_ws
// overflow fixed: r6 used 79 KB of workspace; harness ws appears smaller
// (r3-r5's <=56 KB worked; r6's tail writes corrupted an adjacent buffer ->
// pristine-input corruption -> call-1 pass, later calls deterministically
// wrong). r7 keeps only composition-requiring data in d_ws (41.7 KB):
//   What[128][160] bf16 @0, bhat1[128] f32 @byte 40960, emb[48] f32 after.
// w2/w3/b2 fragments are built in canet_main directly from the fp32 globals
// (aligned float4 loads + v_perm bf16 packs, once per block).
//
// Math (unchanged from r6): h1 = relu(What . im2col(xf) + bhat):
//   What[o][t*16+ic] = sum_r w1[o][4ic+r] * wp[4ic+r][t]  (K=108 -> 160)
//   bhat = b1 + W1 . bp
// GEMM1 B-fragments read directly from staged input rows inS[ky][sx][ic16]:
// k = t*16+icp -> one ds_read_b128 at [ky(t)][px+kx(t)][(q&1)*8], t=2s+(q>>1).
// K-pad (t=9, icp>=12) multiplies What=0 against finite data. 2 barriers/iter.

#define ACT_S 136          // h1/h2 row stride (shorts), 272B, 16B-aligned
#define IN_ROW 4128        // 258*16 shorts per ky row
#define NOISE_BASE 9437184 // 16*9*65536

// d_ws: shorts What[128][160] = [0,20480); floats @ WSF_OFF: bhat1[128], emb[48]
#define WSF_OFF 10240      // float index of float region ( = byte 40960 )
#define WSF_B1 0
#define WSF_EMB 128

typedef short bf16x8 __attribute__((ext_vector_type(8)));
typedef float f32x4 __attribute__((ext_vector_type(4)));

__device__ __forceinline__ short f2bf(float f) {
    union { float f; unsigned u; } cv; cv.f = f;
    unsigned r = cv.u + 0x7FFFu + ((cv.u >> 16) & 1u);
    return (short)(r >> 16);
}
__device__ __forceinline__ short f2bf_fast(float f) {   // round-half-up
    union { float f; unsigned u; } cv; cv.f = f;
    return (short)((cv.u + 0x8000u) >> 16);
}
__device__ __forceinline__ unsigned pk2bf(float f0, float f1) {
    union { float f; unsigned u; } a, b; a.f = f0; b.f = f1;
    return __builtin_amdgcn_perm(b.u + 0x8000u, a.u + 0x8000u, 0x07060302u);
}
__device__ __forceinline__ bf16x8 pk8bf(f32x4 a, f32x4 b) {
    union { unsigned u[4]; bf16x8 v; } r;
    r.u[0] = pk2bf(a[0], a[1]);
    r.u[1] = pk2bf(a[2], a[3]);
    r.u[2] = pk2bf(b[0], b[1]);
    r.u[3] = pk2bf(b[2], b[3]);
    return r.v;
}

// ---------------- weight prep (What, bhat) + time embedding ----------------
__global__ void prep_emb_kernel(const float* __restrict__ wpg, const float* __restrict__ bpg,
                                const float* __restrict__ w1g, const float* __restrict__ b1g,
                                const int* __restrict__ t,
                                const float* __restrict__ wt, const float* __restrict__ bt,
                                short* __restrict__ wsb, float* __restrict__ wsf)
{
    if (blockIdx.x < 81) {
        int i = blockIdx.x * 256 + threadIdx.x;
        if (i < 20480) {                      // What[128][160]
            int o = i / 160, k = i - o * 160;
            int tp = k >> 4, icp = k & 15;
            float val = 0.0f;
            if (tp < 9 && icp < 12) {
                #pragma unroll
                for (int r = 0; r < 4; ++r)
                    val += w1g[o * 48 + icp * 4 + r] * wpg[(icp * 4 + r) * 9 + tp];
            }
            wsb[i] = f2bf(val);
        } else if (i < 20608) {               // bhat1 = b1 + W1.bp
            int o = i - 20480;
            float v = b1g[o];
            for (int oc = 0; oc < 48; ++oc) v += w1g[o * 48 + oc] * bpg[oc];
            wsf[WSF_B1 + o] = v;
        }
        return;
    }
    int b = blockIdx.x - 81;
    int lane = threadIdx.x;
    if (lane >= 64) return;
    float tv = (float)t[b];
    float s0 = 0.f, s1 = 0.f, s2 = 0.f;
    const float LOG1E4 = 9.210340371976184f;
    #pragma unroll
    for (int ii = 0; ii < 2; ++ii) {
        int i = lane + ii * 64;
        float invf = __expf(-LOG1E4 * (float)i * (1.0f / 128.0f));
        float ang = tv * invf;
        float sn = sinf(ang), cs = cosf(ang);
        float ss = sn / (1.0f + __expf(-sn));
        float sc = cs / (1.0f + __expf(-cs));
        s0 += ss * wt[0 * 256 + i] + sc * wt[0 * 256 + i + 128];
        s1 += ss * wt[1 * 256 + i] + sc * wt[1 * 256 + i + 128];
        s2 += ss * wt[2 * 256 + i] + sc * wt[2 * 256 + i + 128];
    }
    #pragma unroll
    for (int off = 32; off; off >>= 1) {
        s0 += __shfl_down(s0, off);
        s1 += __shfl_down(s1, off);
        s2 += __shfl_down(s2, off);
    }
    if (lane == 0) {
        wsf[WSF_EMB + b * 3 + 0] = s0 + bt[0];
        wsf[WSF_EMB + b * 3 + 1] = s1 + bt[1];
        wsf[WSF_EMB + b * 3 + 2] = s2 + bt[2];
    }
}

// ---------------- main fused kernel ----------------
// MFMA 16x16x32 (m89): lane(i=lane&15,q=lane>>4): A[m=i][k=q*8+j],
// B[k=q*8+j][n=i], D col=i, row=q*4+r.
__global__ __launch_bounds__(256, 2) void canet_main(
    const float* __restrict__ xg,   // (16,3,256,256)
    const float* __restrict__ hg,   // (16,9,256,256)
    const float* __restrict__ w2g,  // (128,128) fp32
    const float* __restrict__ b2g,  // (128,) fp32
    const float* __restrict__ w3g,  // (12,128) fp32
    const short* __restrict__ wsb,  // What bf16
    const float* __restrict__ wsf,  // bhat1, emb
    float* __restrict__ outg)
{
    __shared__ __align__(16) short inS[3 * IN_ROW];   // 24.8 KB
    __shared__ __align__(16) short h1S[64 * ACT_S];   // 17.4 KB
    __shared__ __align__(16) short h2S[64 * ACT_S];   // 17.4 KB

    const int tid = threadIdx.x;
    const int bid = blockIdx.x;
    const int b = bid >> 8;
    // y<->XCD swizzle (bijection on low 8 bits): vertical-halo L2 reuse
    const int y = ((bid & 7) << 5) | ((bid >> 3) & 31);

    // ---- zero LDS pads (icp 12..15 everywhere; sx 0 and 257 fully) ----
    for (int i = tid; i < 774; i += 256) {
        int ky = i / 258, sx = i - ky * 258;
        *(uint2*)(inS + ky * IN_ROW + sx * 16 + 12) = uint2{0u, 0u};
    }
    if (tid < 18) {
        int ky = tid / 6, r2 = tid % 6;
        int sx = (r2 & 1) ? 257 : 0, c4 = (r2 >> 1) * 4;
        *(uint2*)(inS + ky * IN_ROW + sx * 16 + c4) = uint2{0u, 0u};
    }

    // ---- stage 3 input rows (y-1,y,y+1), bf16, [sx][ic] interleaved ----
    #pragma unroll
    for (int s = 0; s < 9; ++s) {
        int tk = tid + s * 256;               // 0..2303
        int ky = tk / 768;
        int rem = tk - ky * 768;
        int ch = rem >> 6;
        int x = (rem & 63) << 2;
        int yy = y + ky - 1;
        float4 f = {0.f, 0.f, 0.f, 0.f};
        if (yy >= 0 && yy < 256) {
            const float* src = (ch < 3)
                ? (xg + (((size_t)b * 3 + ch) << 16))
                : (hg + (((size_t)b * 9 + (ch - 3)) << 16));
            f = *(const float4*)(src + yy * 256 + x);
        }
        short* p = inS + ky * IN_ROW + (x + 1) * 16 + ch;
        p[0]  = f2bf_fast(f.x);
        p[16] = f2bf_fast(f.y);
        p[32] = f2bf_fast(f.z);
        p[48] = f2bf_fast(f.w);
    }

    const int wv = tid >> 6;
    const int lane = tid & 63;
    const int i16 = lane & 15;
    const int q = lane >> 4;
    const int qh = q >> 1;
    const int hp = (q & 1) * 8;

    // ---- weight fragments to registers ----
    bf16x8 w1f[2][5], w2f[2][4], w3f[4];
    #pragma unroll
    for (int jt = 0; jt < 2; ++jt) {
        int o = wv * 32 + jt * 16 + i16;
        #pragma unroll
        for (int s = 0; s < 5; ++s)
            w1f[jt][s] = *(const bf16x8*)(wsb + o * 160 + s * 32 + q * 8);
        #pragma unroll
        for (int ks = 0; ks < 4; ++ks) {
            const float* wrow = w2g + o * 128 + ks * 32 + q * 8;
            w2f[jt][ks] = pk8bf(*(const f32x4*)wrow, *(const f32x4*)(wrow + 4));
        }
    }
    #pragma unroll
    for (int ks = 0; ks < 4; ++ks) {
        if (i16 < 12) {
            const float* wrow = w3g + i16 * 128 + ks * 32 + q * 8;
            w3f[ks] = pk8bf(*(const f32x4*)wrow, *(const f32x4*)(wrow + 4));
        } else {
            w3f[ks] = bf16x8{0, 0, 0, 0, 0, 0, 0, 0};
        }
    }

    f32x4 b1v[2], b2v[2];
    #pragma unroll
    for (int jt = 0; jt < 2; ++jt) {
        b1v[jt] = *(const f32x4*)(wsf + WSF_B1 + wv * 32 + jt * 16 + q * 4);
        b2v[jt] = *(const f32x4*)(b2g + wv * 32 + jt * 16 + q * 4);
    }
    const float embv = (i16 < 3) ? wsf[WSF_EMB + b * 3 + i16] : 0.0f;

    // ---- GEMM1 B-address bases: t = 2s+qh -> (ky,kx); t=9 -> dummy (What=0)
    int vb[5];
    #pragma unroll
    for (int s = 0; s < 5; ++s) {
        int tp = 2 * s + qh;
        int ky, kx;
        if (tp > 8) { ky = 0; kx = 0; }
        else { ky = (tp * 11) >> 5; kx = tp - ky * 3; }
        vb[s] = ky * IN_ROW + kx * 16 + hp + i16 * 16;
    }

    __syncthreads();

    #pragma unroll
    for (int it = 0; it < 4; ++it) {
        // ---- GEMM1: h1[ch][px] = relu(What . inS-patches + bhat) ----
        #pragma unroll
        for (int nt = 0; nt < 4; ++nt) {
            f32x4 c0 = b1v[0], c1 = b1v[1];
            #pragma unroll
            for (int s = 0; s < 5; ++s) {
                bf16x8 p = *(const bf16x8*)(inS + vb[s] + (it * 64 + nt * 16) * 16);
                c0 = __builtin_amdgcn_mfma_f32_16x16x32_bf16(w1f[0][s], p, c0, 0, 0, 0);
                c1 = __builtin_amdgcn_mfma_f32_16x16x32_bf16(w1f[1][s], p, c1, 0, 0, 0);
            }
            short* drow = h1S + (nt * 16 + i16) * ACT_S + wv * 32 + q * 4;
            uint2 pk;
            pk.x = pk2bf(fmaxf(c0[0], 0.f), fmaxf(c0[1], 0.f));
            pk.y = pk2bf(fmaxf(c0[2], 0.f), fmaxf(c0[3], 0.f));
            *(uint2*)drow = pk;
            pk.x = pk2bf(fmaxf(c1[0], 0.f), fmaxf(c1[1], 0.f));
            pk.y = pk2bf(fmaxf(c1[2], 0.f), fmaxf(c1[3], 0.f));
            *(uint2*)(drow + 16) = pk;
        }
        __syncthreads();

        // ---- GEMM2: h2[ch][px] = relu(w2 . h1) ----
        #pragma unroll
        for (int nt = 0; nt < 4; ++nt) {
            f32x4 c0 = b2v[0], c1 = b2v[1];
            #pragma unroll
            for (int ks = 0; ks < 4; ++ks) {
                bf16x8 a = *(const bf16x8*)(h1S + (nt * 16 + i16) * ACT_S + ks * 32 + q * 8);
                c0 = __builtin_amdgcn_mfma_f32_16x16x32_bf16(w2f[0][ks], a, c0, 0, 0, 0);
                c1 = __builtin_amdgcn_mfma_f32_16x16x32_bf16(w2f[1][ks], a, c1, 0, 0, 0);
            }
            short* drow = h2S + (nt * 16 + i16) * ACT_S + wv * 32 + q * 4;
            uint2 pk;
            pk.x = pk2bf(fmaxf(c0[0], 0.f), fmaxf(c0[1], 0.f));
            pk.y = pk2bf(fmaxf(c0[2], 0.f), fmaxf(c0[3], 0.f));
            *(uint2*)drow = pk;
            pk.x = pk2bf(fmaxf(c1[0], 0.f), fmaxf(c1[1], 0.f));
            pk.y = pk2bf(fmaxf(c1[2], 0.f), fmaxf(c1[3], 0.f));
            *(uint2*)(drow + 16) = pk;
        }
        __syncthreads();

        // ---- GEMM3: out = h2 . w3^T ; D col=oc, row=px; float4 store ----
        {
            f32x4 acc = {0.f, 0.f, 0.f, 0.f};
            #pragma unroll
            for (int ks = 0; ks < 4; ++ks) {
                bf16x8 a = *(const bf16x8*)(h2S + (wv * 16 + i16) * ACT_S + ks * 32 + q * 8);
                acc = __builtin_amdgcn_mfma_f32_16x16x32_bf16(a, w3f[ks], acc, 0, 0, 0);
            }
            if (i16 < 12) {
                int xx0 = it * 64 + wv * 16 + q * 4;
                size_t idx;
                if (i16 < 3) {
                    idx = (size_t)NOISE_BASE + (((size_t)b * 3 + i16) << 16) + (size_t)y * 256 + xx0;
                } else {
                    idx = (((size_t)b * 9 + (i16 - 3)) << 16) + (size_t)y * 256 + xx0;
                }
                f32x4 vst = {acc[0] + embv, acc[1] + embv, acc[2] + embv, acc[3] + embv};
                *(f32x4*)(outg + idx) = vst;
            }
        }
        // h1S next-iter writes safe: all GEMM2 reads pre-bar2; h2S next-iter
        // writes gated by next bar1 (after all GEMM3 reads).
    }
}

extern "C" void kernel_launch(void* const* d_in, const int* in_sizes, int n_in,
                              void* d_out, int out_size, void* d_ws, size_t ws_size,
                              hipStream_t stream) {
    const float* xg  = (const float*)d_in[0];
    const float* hg  = (const float*)d_in[1];
    const int*   tg  = (const int*)  d_in[2];
    const float* wpg = (const float*)d_in[3];
    const float* bpg = (const float*)d_in[4];
    const float* w1g = (const float*)d_in[5];
    const float* b1g = (const float*)d_in[6];
    const float* w2g = (const float*)d_in[7];
    const float* b2g = (const float*)d_in[8];
    const float* w3g = (const float*)d_in[9];
    const float* wtg = (const float*)d_in[10];
    const float* btg = (const float*)d_in[11];
    float* outg = (float*)d_out;
    short* wsb  = (short*)d_ws;
    float* wsf  = (float*)d_ws + WSF_OFF;

    prep_emb_kernel<<<97, 256, 0, stream>>>(wpg, bpg, w1g, b1g, tg, wtg, btg,
                                            wsb, wsf);
    canet_main<<<4096, 256, 0, stream>>>(xg, hg, w2g, b2g, w3g, wsb, wsf, outg);
}